// Round 6
// baseline (3876.675 us; speedup 1.0000x reference)
//
#include <hip/hip_runtime.h>
#include <hip/hip_bf16.h>

#define EDIM 256
#define HDIM 512
#define BB 32
#define SS 512
#define CC 2
#define G3 1536   // 3*HDIM

typedef unsigned int u32;
typedef unsigned long long u64;
typedef __attribute__((ext_vector_type(8))) short short8;
typedef __attribute__((ext_vector_type(4))) float f32x4;

__device__ __forceinline__ float toF(float v) { return v; }
__device__ __forceinline__ float toF(__hip_bfloat16 v) { return __bfloat162float(v); }
__device__ __forceinline__ void storeX(float* p, float v) { *p = v; }
__device__ __forceinline__ void storeX(__hip_bfloat16* p, float v) { *p = __float2bfloat16(v); }

// fp32 -> bf16 bits, round-to-nearest-even
__device__ __forceinline__ unsigned short f2bf(float f) {
  u32 b = __float_as_uint(f);
  return (unsigned short)((b + 0x7FFFu + ((b >> 16) & 1u)) >> 16);
}

// ---------------- K1: zero tagged h words (wgs 0..15) + induced vec (wg 16) ------------------------
__global__ void k_init(const float* __restrict__ induction, const float* __restrict__ unk_vec,
                       float* __restrict__ induced, u64* __restrict__ thw) {
  const int t = threadIdx.x;
  const int wg = blockIdx.x;
  if (wg < 16) {
    u64* p = thw + (size_t)wg * 1024;
    for (int i = t; i < 1024; i += 256) p[i] = 0ull;
  } else {
    float acc = 0.f;
    const float* row = induction + t * EDIM;
#pragma unroll 4
    for (int j = 0; j < EDIM; j += 4) {
      float4 a = *(const float4*)(row + j);
      float4 u = *(const float4*)(unk_vec + j);
      acc += a.x * u.x + a.y * u.y + a.z * u.z + a.w * u.w;
    }
    induced[t] = acc;
  }
}

// ---------------- K2: xi = gather(e) @ W_ih^T + b_ih via bf16 MFMA ----------------------------------
template <typename XT>
__global__ __launch_bounds__(256) void k_xi(const int* __restrict__ x, const float* __restrict__ emb,
                                            const float* __restrict__ induced,
                                            const float* __restrict__ W_ih, const float* __restrict__ b_ih,
                                            XT* __restrict__ xi) {
  __shared__ __align__(16) unsigned short As[128][40];
  __shared__ __align__(16) unsigned short Bs[128][40];
  __shared__ int toks[128];
  __shared__ float bcol[128];
  const int c0 = blockIdx.x * 128;
  const int r0 = blockIdx.y * 128;
  const int tid = threadIdx.x;
  if (tid < 128) { toks[tid] = x[r0 + tid]; bcol[tid] = b_ih[c0 + tid]; }
  __syncthreads();

  const int wv = tid >> 6, ln = tid & 63;
  const int lr = tid & 127, kh = tid >> 7;
  const int fm = ln & 15, fq = ln >> 4;

  f32x4 acc[2][8];
#pragma unroll
  for (int i = 0; i < 2; i++)
#pragma unroll
    for (int j = 0; j < 8; j++) acc[i][j] = (f32x4){0.f, 0.f, 0.f, 0.f};

  const int tok = toks[lr];
  const float* abase = (tok < 0 ? induced : emb + (size_t)tok * EDIM) + kh * 16;
  const float* bbase = W_ih + (size_t)(c0 + lr) * EDIM + kh * 16;

  for (int kk = 0; kk < EDIM; kk += 32) {
    unsigned short av[16], bv[16];
#pragma unroll
    for (int q = 0; q < 4; q++) {
      float4 ta = *(const float4*)(abase + kk + q * 4);
      float4 tb = *(const float4*)(bbase + kk + q * 4);
      av[q * 4 + 0] = f2bf(ta.x); av[q * 4 + 1] = f2bf(ta.y);
      av[q * 4 + 2] = f2bf(ta.z); av[q * 4 + 3] = f2bf(ta.w);
      bv[q * 4 + 0] = f2bf(tb.x); bv[q * 4 + 1] = f2bf(tb.y);
      bv[q * 4 + 2] = f2bf(tb.z); bv[q * 4 + 3] = f2bf(tb.w);
    }
    *(uint4*)&As[lr][kh * 16 + 0] = *(uint4*)&av[0];
    *(uint4*)&As[lr][kh * 16 + 8] = *(uint4*)&av[8];
    *(uint4*)&Bs[lr][kh * 16 + 0] = *(uint4*)&bv[0];
    *(uint4*)&Bs[lr][kh * 16 + 8] = *(uint4*)&bv[8];
    __syncthreads();

    short8 af0 = *(const short8*)&As[wv * 32 + fm][fq * 8];
    short8 af1 = *(const short8*)&As[wv * 32 + 16 + fm][fq * 8];
#pragma unroll
    for (int ni = 0; ni < 8; ni++) {
      short8 bf = *(const short8*)&Bs[ni * 16 + fm][fq * 8];
      acc[0][ni] = __builtin_amdgcn_mfma_f32_16x16x32_bf16(af0, bf, acc[0][ni], 0, 0, 0);
      acc[1][ni] = __builtin_amdgcn_mfma_f32_16x16x32_bf16(af1, bf, acc[1][ni], 0, 0, 0);
    }
    __syncthreads();
  }

#pragma unroll
  for (int mi = 0; mi < 2; mi++)
#pragma unroll
    for (int ni = 0; ni < 8; ni++) {
      const int col = c0 + ni * 16 + fm;
      const float bb = bcol[ni * 16 + fm];
#pragma unroll
      for (int r = 0; r < 4; r++) {
        const int row = r0 + wv * 32 + mi * 16 + fq * 4 + r;
        storeX(xi + (size_t)row * G3 + col, acc[mi][ni][r] + bb);
      }
    }
}

// ---------------- K3: persistent GRU, tagged exchange + in-wave butterfly reduction ----------------
// 8 groups x 32 wgs (same-XCD under %8 round-robin). Half-wave i2 owns units {i0+2*i2, i0+2*i2+1}
// for all 4 chains; ks = lane-in-half-wave = k-slice. Partial dots -> 5-step shfl_xor butterfly
// (sum over ks) -> lanes 0..7 of each half-wave compute gates for (chain=ks>>1, unit ii=ks&1) ->
// publish packed tagged word immediately. One barrier per step (h staging).
template <typename XT>
__global__ __launch_bounds__(256, 1) void k_gru(const XT* __restrict__ xi, const float* __restrict__ W_hh,
                                                const float* __restrict__ b_hh, u64* __restrict__ thw,
                                                float* __restrict__ pooled) {
  const int wg = blockIdx.x;
  const int g = wg & 7;
  const int m = wg >> 3;
  const int bbase = g * 4;
  const int i0 = m * 16;
  const int tid = threadIdx.x;
  const int i2 = tid >> 5;     // half-wave id 0..7
  const int ks = tid & 31;     // lane in half-wave

  float2 w[2][3][8];  // W_hh slice: units i0+2*i2+{0,1}, k = ks*2 + j*64
#pragma unroll
  for (int ii = 0; ii < 2; ii++) {
    const int i = i0 + i2 * 2 + ii;
#pragma unroll
    for (int q = 0; q < 3; q++) {
      const float* wrow = W_hh + (size_t)(q * HDIM + i) * HDIM;
#pragma unroll
      for (int j = 0; j < 8; j++) w[ii][q][j] = *(const float2*)(wrow + ks * 2 + j * 64);
    }
  }

  // gate-lane mapping: lanes ks<8 of each half-wave
  const bool isg = ks < 8;
  const int gb4 = (ks >> 1) & 3;   // chain within group
  const int gii = ks & 1;          // which unit of the pair
  const int gunit = i0 + i2 * 2 + gii;
  float bh0 = 0.f, bh1 = 0.f, bh2 = 0.f;
  if (isg) {
    bh0 = b_hh[0 * HDIM + gunit];
    bh1 = b_hh[1 * HDIM + gunit];
    bh2 = b_hh[2 * HDIM + gunit];
  }

  u64* slot = thw + (size_t)g * 2 * 1024;

  __shared__ float hs[2][4][512];

  float pmax = -3.0e38f;

  float cxr = 0.f, cxz = 0.f, cxn = 0.f;
  if (isg) {
    const size_t xo = (size_t)(bbase + gb4) * SS * G3 + gunit;
    cxr = toF(xi[xo]); cxz = toF(xi[xo + HDIM]); cxn = toF(xi[xo + 2 * HDIM]);
  }

  for (int s = 0; s < SS; s++) {
    float* hcur = &hs[s & 1][0][0];
    if (s == 0) {
#pragma unroll
      for (int j = 0; j < 8; j++) hcur[j * 256 + tid] = 0.f;
    } else {
      const u64* src = slot + (size_t)(s & 1) * 1024 + tid;  // word j*256+tid: chain j, pair tid
      const u32 need = (u32)s;
      u64 v[4];
#pragma unroll
      for (int j = 0; j < 4; j++)
        v[j] = __hip_atomic_load(src + j * 256, __ATOMIC_RELAXED, __HIP_MEMORY_SCOPE_AGENT);
      u32 pend = 0;
#pragma unroll
      for (int j = 0; j < 4; j++)
        if ((u32)(v[j] & 0xFFFFu) != need) pend |= 1u << j;
      int guard = 0;
      while (pend && guard < (1 << 20)) {
        __builtin_amdgcn_s_sleep(1);
#pragma unroll
        for (int j = 0; j < 4; j++)
          if (pend & (1u << j))
            v[j] = __hip_atomic_load(src + j * 256, __ATOMIC_RELAXED, __HIP_MEMORY_SCOPE_AGENT);
#pragma unroll
        for (int j = 0; j < 4; j++)
          if ((pend & (1u << j)) && (u32)(v[j] & 0xFFFFu) == need) pend &= ~(1u << j);
        guard++;
      }
#pragma unroll
      for (int j = 0; j < 4; j++) {
        const float a = __uint_as_float((u32)(v[j] >> 40) << 8);
        const float b = __uint_as_float((u32)((v[j] >> 16) & 0xFFFFFFu) << 8);
        *(float2*)&hcur[j * 512 + 2 * tid] = make_float2(a, b);
      }
    }
    __syncthreads();  // the ONLY barrier per step

    // prefetch next xi here: HBM latency overlaps compute, not the next poll
    float nxr = 0.f, nxz = 0.f, nxn = 0.f;
    if (isg && s + 1 < SS) {
      const size_t xo = ((size_t)(bbase + gb4) * SS + (s + 1)) * G3 + gunit;
      nxr = toF(xi[xo]); nxz = toF(xi[xo + HDIM]); nxn = toF(xi[xo + 2 * HDIM]);
    }

    // partial dots: A[chain][g], g = ii*3+q
    float A[4][6];
#pragma unroll
    for (int b4 = 0; b4 < 4; b4++) {
      float a00 = 0.f, a01 = 0.f, a02 = 0.f, a10 = 0.f, a11 = 0.f, a12 = 0.f;
#pragma unroll
      for (int j = 0; j < 8; j++) {
        const float2 hv = *(const float2*)&hcur[b4 * 512 + ks * 2 + j * 64];
        a00 += w[0][0][j].x * hv.x + w[0][0][j].y * hv.y;
        a01 += w[0][1][j].x * hv.x + w[0][1][j].y * hv.y;
        a02 += w[0][2][j].x * hv.x + w[0][2][j].y * hv.y;
        a10 += w[1][0][j].x * hv.x + w[1][0][j].y * hv.y;
        a11 += w[1][1][j].x * hv.x + w[1][1][j].y * hv.y;
        a12 += w[1][2][j].x * hv.x + w[1][2][j].y * hv.y;
      }
      A[b4][0] = a00; A[b4][1] = a01; A[b4][2] = a02;
      A[b4][3] = a10; A[b4][4] = a11; A[b4][5] = a12;
    }

    // butterfly: sum over the 32 lanes (ks) of each half-wave
#pragma unroll
    for (int st = 1; st <= 16; st <<= 1) {
#pragma unroll
      for (int b4 = 0; b4 < 4; b4++)
#pragma unroll
        for (int q = 0; q < 6; q++) A[b4][q] += __shfl_xor(A[b4][q], st, 64);
    }

    // gates in lanes 0..7 of each half-wave
    if (isg) {
      const float hr = bh0 + (gii ? A[gb4][3] : A[gb4][0]);
      const float hz = bh1 + (gii ? A[gb4][4] : A[gb4][1]);
      const float hn = bh2 + (gii ? A[gb4][5] : A[gb4][2]);
      const float r = 1.f / (1.f + expf(-(cxr + hr)));
      const float z = 1.f / (1.f + expf(-(cxz + hz)));
      const float n = tanhf(cxn + r * hn);
      const float hp = hcur[gb4 * 512 + gunit];
      const float hnew = (1.f - z) * n + z * hp;
      pmax = fmaxf(pmax, hnew);
      const float pv = __shfl_xor(hnew, 1, 64);  // partner unit of the pair
      if (gii == 0) {
        const u32 abits = ((__float_as_uint(hnew) + 0x80u) >> 8) & 0xFFFFFFu;
        const u32 bbits = ((__float_as_uint(pv) + 0x80u) >> 8) & 0xFFFFFFu;
        const u64 pkt = ((u64)abits << 40) | ((u64)bbits << 16) | (u64)(u32)(s + 1);
        const int W = gb4 * 256 + (i0 >> 1) + i2;
        __hip_atomic_store(slot + (size_t)((s + 1) & 1) * 1024 + W, pkt,
                           __ATOMIC_RELAXED, __HIP_MEMORY_SCOPE_AGENT);
      }
    }
    cxr = nxr; cxz = nxz; cxn = nxn;
  }

  if (isg) pooled[(size_t)(bbase + gb4) * HDIM + gunit] = pmax;
}

// ---------------- K4: out = pooled @ W_proj^T + b_proj ----------------------------------------------
__global__ void k_out(const float* __restrict__ pooled, const float* __restrict__ W_proj,
                      const float* __restrict__ b_proj, float* __restrict__ out) {
  const int t = threadIdx.x;  // 64 threads
  const int b = t >> 1, c = t & 1;
  const float* p = pooled + (size_t)b * HDIM;
  const float* wr = W_proj + (size_t)c * HDIM;
  float acc = 0.f;
#pragma unroll 4
  for (int k = 0; k < HDIM; k += 4) {
    float4 pv = *(const float4*)(p + k);
    float4 wv = *(const float4*)(wr + k);
    acc += pv.x * wv.x + pv.y * wv.y + pv.z * wv.z + pv.w * wv.w;
  }
  out[b * CC + c] = acc + b_proj[c];
}

extern "C" void kernel_launch(void* const* d_in, const int* in_sizes, int n_in,
                              void* d_out, int out_size, void* d_ws, size_t ws_size,
                              hipStream_t stream) {
  const int* x = (const int*)d_in[0];
  const float* emb = (const float*)d_in[1];
  const float* unk = (const float*)d_in[2];
  const float* induction = (const float*)d_in[3];
  const float* W_ih = (const float*)d_in[4];
  const float* W_hh = (const float*)d_in[5];
  const float* b_ih = (const float*)d_in[6];
  const float* b_hh = (const float*)d_in[7];
  const float* W_proj = (const float*)d_in[8];
  const float* b_proj = (const float*)d_in[9];
  float* out = (float*)d_out;

  const size_t xi_f32 = (size_t)BB * SS * G3 * 4;
  const size_t xi_b16 = (size_t)BB * SS * G3 * 2;
  const size_t thw_sz = (size_t)8 * 2 * 1024 * 8;  // 128 KB
  const size_t tail = thw_sz + (size_t)BB * HDIM * 4 + EDIM * 4 + 4096;
  const bool usef32 = ws_size >= xi_f32 + tail;

  char* p = (char*)d_ws;
  void* xi = p;
  p += ((usef32 ? xi_f32 : xi_b16) + 255) & ~(size_t)255;
  u64* thw = (u64*)p;         p += thw_sz;
  float* pooled = (float*)p;  p += (size_t)BB * HDIM * 4;
  float* induced = (float*)p;

  k_init<<<17, 256, 0, stream>>>(induction, unk, induced, thw);
  if (usef32) {
    k_xi<float><<<dim3(12, 128), 256, 0, stream>>>(x, emb, induced, W_ih, b_ih, (float*)xi);
    k_gru<float><<<256, 256, 0, stream>>>((const float*)xi, W_hh, b_hh, thw, pooled);
  } else {
    k_xi<__hip_bfloat16><<<dim3(12, 128), 256, 0, stream>>>(x, emb, induced, W_ih, b_ih,
                                                            (__hip_bfloat16*)xi);
    k_gru<__hip_bfloat16><<<256, 256, 0, stream>>>((const __hip_bfloat16*)xi, W_hh, b_hh, thw, pooled);
  }
  k_out<<<1, 64, 0, stream>>>(pooled, W_proj, b_proj, out);
}

// Round 7
// 2244.555 us; speedup vs baseline: 1.7271x; 1.7271x over previous
//
#include <hip/hip_runtime.h>
#include <hip/hip_bf16.h>

#define EDIM 256
#define HDIM 512
#define BB 32
#define SS 512
#define CC 2
#define G3 1536   // 3*HDIM

typedef unsigned int u32;
typedef unsigned long long u64;
typedef __attribute__((ext_vector_type(8))) short short8;
typedef __attribute__((ext_vector_type(4))) float f32x4;
typedef __attribute__((ext_vector_type(4))) u32 u32x4;

__device__ __forceinline__ float toF(float v) { return v; }
__device__ __forceinline__ float toF(__hip_bfloat16 v) { return __bfloat162float(v); }
__device__ __forceinline__ void storeX(float* p, float v) { *p = v; }
__device__ __forceinline__ void storeX(__hip_bfloat16* p, float v) { *p = __float2bfloat16(v); }

__device__ __forceinline__ unsigned short f2bf(float f) {
  u32 b = __float_as_uint(f);
  return (unsigned short)((b + 0x7FFFu + ((b >> 16) & 1u)) >> 16);
}

// ---------------- K1: zero tagged h words + induced vec ---------------------------------------------
__global__ void k_init(const float* __restrict__ induction, const float* __restrict__ unk_vec,
                       float* __restrict__ induced, u64* __restrict__ thw) {
  const int t = threadIdx.x;
  const int wg = blockIdx.x;
  if (wg < 16) {
    u64* p = thw + (size_t)wg * 1024;
    for (int i = t; i < 1024; i += 256) p[i] = 0ull;
  } else {
    float acc = 0.f;
    const float* row = induction + t * EDIM;
#pragma unroll 4
    for (int j = 0; j < EDIM; j += 4) {
      float4 a = *(const float4*)(row + j);
      float4 u = *(const float4*)(unk_vec + j);
      acc += a.x * u.x + a.y * u.y + a.z * u.z + a.w * u.w;
    }
    induced[t] = acc;
  }
}

// ---------------- K2: xi = gather(e) @ W_ih^T + b_ih via bf16 MFMA ----------------------------------
template <typename XT>
__global__ __launch_bounds__(256) void k_xi(const int* __restrict__ x, const float* __restrict__ emb,
                                            const float* __restrict__ induced,
                                            const float* __restrict__ W_ih, const float* __restrict__ b_ih,
                                            XT* __restrict__ xi) {
  __shared__ __align__(16) unsigned short As[128][40];
  __shared__ __align__(16) unsigned short Bs[128][40];
  __shared__ int toks[128];
  __shared__ float bcol[128];
  const int c0 = blockIdx.x * 128;
  const int r0 = blockIdx.y * 128;
  const int tid = threadIdx.x;
  if (tid < 128) { toks[tid] = x[r0 + tid]; bcol[tid] = b_ih[c0 + tid]; }
  __syncthreads();

  const int wv = tid >> 6, ln = tid & 63;
  const int lr = tid & 127, kh = tid >> 7;
  const int fm = ln & 15, fq = ln >> 4;

  f32x4 acc[2][8];
#pragma unroll
  for (int i = 0; i < 2; i++)
#pragma unroll
    for (int j = 0; j < 8; j++) acc[i][j] = (f32x4){0.f, 0.f, 0.f, 0.f};

  const int tok = toks[lr];
  const float* abase = (tok < 0 ? induced : emb + (size_t)tok * EDIM) + kh * 16;
  const float* bbase = W_ih + (size_t)(c0 + lr) * EDIM + kh * 16;

  for (int kk = 0; kk < EDIM; kk += 32) {
    unsigned short av[16], bv[16];
#pragma unroll
    for (int q = 0; q < 4; q++) {
      float4 ta = *(const float4*)(abase + kk + q * 4);
      float4 tb = *(const float4*)(bbase + kk + q * 4);
      av[q * 4 + 0] = f2bf(ta.x); av[q * 4 + 1] = f2bf(ta.y);
      av[q * 4 + 2] = f2bf(ta.z); av[q * 4 + 3] = f2bf(ta.w);
      bv[q * 4 + 0] = f2bf(tb.x); bv[q * 4 + 1] = f2bf(tb.y);
      bv[q * 4 + 2] = f2bf(tb.z); bv[q * 4 + 3] = f2bf(tb.w);
    }
    *(uint4*)&As[lr][kh * 16 + 0] = *(uint4*)&av[0];
    *(uint4*)&As[lr][kh * 16 + 8] = *(uint4*)&av[8];
    *(uint4*)&Bs[lr][kh * 16 + 0] = *(uint4*)&bv[0];
    *(uint4*)&Bs[lr][kh * 16 + 8] = *(uint4*)&bv[8];
    __syncthreads();

    short8 af0 = *(const short8*)&As[wv * 32 + fm][fq * 8];
    short8 af1 = *(const short8*)&As[wv * 32 + 16 + fm][fq * 8];
#pragma unroll
    for (int ni = 0; ni < 8; ni++) {
      short8 bf = *(const short8*)&Bs[ni * 16 + fm][fq * 8];
      acc[0][ni] = __builtin_amdgcn_mfma_f32_16x16x32_bf16(af0, bf, acc[0][ni], 0, 0, 0);
      acc[1][ni] = __builtin_amdgcn_mfma_f32_16x16x32_bf16(af1, bf, acc[1][ni], 0, 0, 0);
    }
    __syncthreads();
  }

#pragma unroll
  for (int mi = 0; mi < 2; mi++)
#pragma unroll
    for (int ni = 0; ni < 8; ni++) {
      const int col = c0 + ni * 16 + fm;
      const float bb = bcol[ni * 16 + fm];
#pragma unroll
      for (int r = 0; r < 4; r++) {
        const int row = r0 + wv * 32 + mi * 16 + fq * 4 + r;
        storeX(xi + (size_t)row * G3 + col, acc[mi][ni][r] + bb);
      }
    }
}

// ---------------- K3: persistent GRU -----------------------------------------------------------------
// R5 skeleton (LDS reduce, wave-0 gates, coalesced 64B publishes) + pair-major exchange layout:
// word idx = pair*4 + chain, pair = unit/2. Thread tid polls its 32B block (4 words) with two
// coherent dwordx4 loads (sc0 sc1 == device-scope relaxed atomic semantics, but coalesced).
template <typename XT>
__global__ __launch_bounds__(256, 1) void k_gru(const XT* __restrict__ xi, const float* __restrict__ W_hh,
                                                const float* __restrict__ b_hh, u64* __restrict__ thw,
                                                float* __restrict__ pooled) {
  const int wg = blockIdx.x;
  const int g = wg & 7;
  const int m = wg >> 3;
  const int bbase = g * 4;
  const int i0 = m * 16;
  const int tid = threadIdx.x;
  const int i2 = tid >> 5;
  const int ks = tid & 31;

  float2 w[2][3][8];  // 96 fp32 W_hh slice
#pragma unroll
  for (int ii = 0; ii < 2; ii++) {
    const int i = i0 + i2 * 2 + ii;
#pragma unroll
    for (int q = 0; q < 3; q++) {
      const float* wrow = W_hh + (size_t)(q * HDIM + i) * HDIM;
#pragma unroll
      for (int j = 0; j < 8; j++) w[ii][q][j] = *(const float2*)(wrow + ks * 2 + j * 64);
    }
  }
  // pin the weights in VGPRs — defeat the compiler's loop-sinking of these loads (R5: VGPR_Count=76
  // proved they were re-streamed every step)
#pragma unroll
  for (int ii = 0; ii < 2; ii++)
#pragma unroll
    for (int q = 0; q < 3; q++)
#pragma unroll
      for (int j = 0; j < 8; j++)
        asm volatile("" : "+v"(w[ii][q][j].x), "+v"(w[ii][q][j].y));

  const int ilg = tid & 15;
  const int b4g = tid >> 4;  // for tid<64
  const float bh0 = b_hh[0 * HDIM + i0 + ilg];
  const float bh1 = b_hh[1 * HDIM + i0 + ilg];
  const float bh2 = b_hh[2 * HDIM + i0 + ilg];

  u64* slot = thw + (size_t)g * 2 * 1024;

  __shared__ float hs[2][4][512];
  __shared__ float red[192][34];
  __shared__ float gsum[208];

  float pmax = -3.0e38f;

  float cxr = 0.f, cxz = 0.f, cxn = 0.f;
  if (tid < 64) {
    const size_t xo = (size_t)(bbase + b4g) * SS * G3 + (i0 + ilg);
    cxr = toF(xi[xo]); cxz = toF(xi[xo + HDIM]); cxn = toF(xi[xo + 2 * HDIM]);
  }

  for (int s = 0; s < SS; s++) {
    // prefetch next step's xi (consumed at loop end; latency hides under poll+compute)
    float nxr = 0.f, nxz = 0.f, nxn = 0.f;
    if (tid < 64 && s + 1 < SS) {
      const size_t xo = ((size_t)(bbase + b4g) * SS + (s + 1)) * G3 + (i0 + ilg);
      nxr = toF(xi[xo]); nxz = toF(xi[xo + HDIM]); nxn = toF(xi[xo + 2 * HDIM]);
    }

    float* hcur = &hs[s & 1][0][0];
    if (s == 0) {
#pragma unroll
      for (int j = 0; j < 8; j++) hcur[j * 256 + tid] = 0.f;
    } else {
      const u64* src = slot + (size_t)(s & 1) * 1024 + (size_t)tid * 4;
      const u32 need = (u32)s;
      u32x4 lo, hi;  // words 0,1 (chains 0,1) and 2,3 (chains 2,3)
      int guard = 0;
      for (;;) {
        asm volatile(
            "global_load_dwordx4 %0, %2, off sc0 sc1\n\t"
            "global_load_dwordx4 %1, %2, off offset:16 sc0 sc1\n\t"
            "s_waitcnt vmcnt(0)"
            : "=v"(lo), "=v"(hi)
            : "v"(src)
            : "memory");
        const bool ok = ((lo.x & 0xFFFFu) == need) & ((lo.z & 0xFFFFu) == need) &
                        ((hi.x & 0xFFFFu) == need) & ((hi.z & 0xFFFFu) == need);
        if (ok) break;
        if (++guard > (1 << 20)) break;
        __builtin_amdgcn_s_sleep(1);
      }
      // unpack word (lo32,hi32): a = hi32&~0xFF ; b = ((hi32&0xFF)<<24)|((lo32>>16)<<8)
      {
        const float a0 = __uint_as_float(lo.y & 0xFFFFFF00u);
        const float b0 = __uint_as_float(((lo.y & 0xFFu) << 24) | ((lo.x >> 16) << 8));
        const float a1 = __uint_as_float(lo.w & 0xFFFFFF00u);
        const float b1 = __uint_as_float(((lo.w & 0xFFu) << 24) | ((lo.z >> 16) << 8));
        const float a2 = __uint_as_float(hi.y & 0xFFFFFF00u);
        const float b2 = __uint_as_float(((hi.y & 0xFFu) << 24) | ((hi.x >> 16) << 8));
        const float a3 = __uint_as_float(hi.w & 0xFFFFFF00u);
        const float b3 = __uint_as_float(((hi.w & 0xFFu) << 24) | ((hi.z >> 16) << 8));
        *(float2*)&hcur[0 * 512 + 2 * tid] = make_float2(a0, b0);
        *(float2*)&hcur[1 * 512 + 2 * tid] = make_float2(a1, b1);
        *(float2*)&hcur[2 * 512 + 2 * tid] = make_float2(a2, b2);
        *(float2*)&hcur[3 * 512 + 2 * tid] = make_float2(a3, b3);
      }
    }
    __syncthreads();  // S1: h staged

    // partial dots
#pragma unroll
    for (int b4 = 0; b4 < 4; b4++) {
      float a00 = 0.f, a01 = 0.f, a02 = 0.f, a10 = 0.f, a11 = 0.f, a12 = 0.f;
#pragma unroll
      for (int j = 0; j < 8; j++) {
        const float2 hv = *(const float2*)&hcur[b4 * 512 + ks * 2 + j * 64];
        a00 += w[0][0][j].x * hv.x + w[0][0][j].y * hv.y;
        a01 += w[0][1][j].x * hv.x + w[0][1][j].y * hv.y;
        a02 += w[0][2][j].x * hv.x + w[0][2][j].y * hv.y;
        a10 += w[1][0][j].x * hv.x + w[1][0][j].y * hv.y;
        a11 += w[1][1][j].x * hv.x + w[1][1][j].y * hv.y;
        a12 += w[1][2][j].x * hv.x + w[1][2][j].y * hv.y;
      }
      const int o0 = (i2 * 2) * 12 + b4 * 3;
      red[o0 + 0][ks] = a00; red[o0 + 1][ks] = a01; red[o0 + 2][ks] = a02;
      red[o0 + 12][ks] = a10; red[o0 + 13][ks] = a11; red[o0 + 14][ks] = a12;
    }
    __syncthreads();  // S2

    if (tid < 192) {
      float acc = 0.f;
      const float* r = &red[tid][0];
#pragma unroll
      for (int k = 0; k < 32; k += 2) {
        const float2 t2 = *(const float2*)(r + k);
        acc += t2.x + t2.y;
      }
      gsum[tid] = acc;
    }
    __syncthreads();  // S3

    if (tid < 64) {
      const int c0i = ilg * 12 + b4g * 3;
      const float hr = bh0 + gsum[c0i + 0];
      const float hz = bh1 + gsum[c0i + 1];
      const float hn = bh2 + gsum[c0i + 2];
      const float r = 1.f / (1.f + expf(-(cxr + hr)));
      const float z = 1.f / (1.f + expf(-(cxz + hz)));
      const float n = tanhf(cxn + r * hn);
      const float hp = hcur[b4g * 512 + i0 + ilg];
      const float hnew = (1.f - z) * n + z * hp;
      pmax = fmaxf(pmax, hnew);
      const float pv = __shfl_xor(hnew, 1, 64);  // partner unit (ilg^1)
      if ((ilg & 1) == 0) {
        const u32 abits = ((__float_as_uint(hnew) + 0x80u) >> 8) & 0xFFFFFFu;
        const u32 bbits = ((__float_as_uint(pv) + 0x80u) >> 8) & 0xFFFFFFu;
        const u64 pkt = ((u64)abits << 40) | ((u64)bbits << 16) | (u64)(u32)(s + 1);
        const int W = ((i0 >> 1) + (ilg >> 1)) * 4 + b4g;  // pair-major layout
        __hip_atomic_store(slot + (size_t)((s + 1) & 1) * 1024 + W, pkt,
                           __ATOMIC_RELAXED, __HIP_MEMORY_SCOPE_AGENT);
      }
    }
    cxr = nxr; cxz = nxz; cxn = nxn;
  }

  if (tid < 64) pooled[(size_t)(bbase + b4g) * HDIM + i0 + ilg] = pmax;
}

// ---------------- K4: out = pooled @ W_proj^T + b_proj ----------------------------------------------
__global__ void k_out(const float* __restrict__ pooled, const float* __restrict__ W_proj,
                      const float* __restrict__ b_proj, float* __restrict__ out) {
  const int t = threadIdx.x;  // 64 threads
  const int b = t >> 1, c = t & 1;
  const float* p = pooled + (size_t)b * HDIM;
  const float* wr = W_proj + (size_t)c * HDIM;
  float acc = 0.f;
#pragma unroll 4
  for (int k = 0; k < HDIM; k += 4) {
    float4 pv = *(const float4*)(p + k);
    float4 wv = *(const float4*)(wr + k);
    acc += pv.x * wv.x + pv.y * wv.y + pv.z * wv.z + pv.w * wv.w;
  }
  out[b * CC + c] = acc + b_proj[c];
}

extern "C" void kernel_launch(void* const* d_in, const int* in_sizes, int n_in,
                              void* d_out, int out_size, void* d_ws, size_t ws_size,
                              hipStream_t stream) {
  const int* x = (const int*)d_in[0];
  const float* emb = (const float*)d_in[1];
  const float* unk = (const float*)d_in[2];
  const float* induction = (const float*)d_in[3];
  const float* W_ih = (const float*)d_in[4];
  const float* W_hh = (const float*)d_in[5];
  const float* b_ih = (const float*)d_in[6];
  const float* b_hh = (const float*)d_in[7];
  const float* W_proj = (const float*)d_in[8];
  const float* b_proj = (const float*)d_in[9];
  float* out = (float*)d_out;

  const size_t xi_f32 = (size_t)BB * SS * G3 * 4;
  const size_t xi_b16 = (size_t)BB * SS * G3 * 2;
  const size_t thw_sz = (size_t)8 * 2 * 1024 * 8;  // 128 KB
  const size_t tail = thw_sz + (size_t)BB * HDIM * 4 + EDIM * 4 + 4096;
  const bool usef32 = ws_size >= xi_f32 + tail;

  char* p = (char*)d_ws;
  void* xi = p;
  p += ((usef32 ? xi_f32 : xi_b16) + 255) & ~(size_t)255;
  u64* thw = (u64*)p;         p += thw_sz;
  float* pooled = (float*)p;  p += (size_t)BB * HDIM * 4;
  float* induced = (float*)p;

  k_init<<<17, 256, 0, stream>>>(induction, unk, induced, thw);
  if (usef32) {
    k_xi<float><<<dim3(12, 128), 256, 0, stream>>>(x, emb, induced, W_ih, b_ih, (float*)xi);
    k_gru<float><<<256, 256, 0, stream>>>((const float*)xi, W_hh, b_hh, thw, pooled);
  } else {
    k_xi<__hip_bfloat16><<<dim3(12, 128), 256, 0, stream>>>(x, emb, induced, W_ih, b_ih,
                                                            (__hip_bfloat16*)xi);
    k_gru<__hip_bfloat16><<<256, 256, 0, stream>>>((const __hip_bfloat16*)xi, W_hh, b_hh, thw, pooled);
  }
  k_out<<<1, 64, 0, stream>>>(pooled, W_proj, b_proj, out);
}